// Round 1
// baseline (90.999 us; speedup 1.0000x reference)
//
#include <hip/hip_runtime.h>
#include <math.h>

// CSR segment-max graph pooling:
//   out[i,:] = max over e in [indptr[i], indptr[i+1]) of x[indices[e], :]
// N=100000 nodes, D=32 f32 features, uniform degree 16.
//
// Mapping: 8 lanes per node, each lane owns one float4 (16B) chunk of the
// D=32 row. A gathered row = 8 lanes x 16B = one coalesced 128B transaction.
// 256-thread block = 32 nodes. Fast path (deg==16, 4-aligned start) loads
// the 16 indices as 4x int4 and fully unrolls the gathers for 16-deep ILP.

#define LANES_PER_NODE 8
#define NODES_PER_BLOCK 32   // 256 threads / 8

__global__ __launch_bounds__(256) void seg_max_kernel(
    const float* __restrict__ x,
    const int* __restrict__ indptr,
    const int* __restrict__ indices,
    float* __restrict__ out,
    int n_nodes)
{
    const int c    = threadIdx.x & (LANES_PER_NODE - 1);   // float4 chunk 0..7
    const int node = blockIdx.x * NODES_PER_BLOCK + (threadIdx.x >> 3);
    if (node >= n_nodes) return;

    const int start = indptr[node];
    const int end   = indptr[node + 1];
    const int deg   = end - start;

    const float4* __restrict__ x4 = reinterpret_cast<const float4*>(x);

    float4 acc = make_float4(-INFINITY, -INFINITY, -INFINITY, -INFINITY);

    if (deg == 16 && ((start & 3) == 0)) {
        // Fast path: vector-load all 16 indices, fully unroll -> 16
        // independent dwordx4 gathers in flight per lane.
        const int4* __restrict__ idx4 =
            reinterpret_cast<const int4*>(indices + start);
        const int4 i0 = idx4[0];
        const int4 i1 = idx4[1];
        const int4 i2 = idx4[2];
        const int4 i3 = idx4[3];
        int rows[16] = { i0.x, i0.y, i0.z, i0.w,
                         i1.x, i1.y, i1.z, i1.w,
                         i2.x, i2.y, i2.z, i2.w,
                         i3.x, i3.y, i3.z, i3.w };
        #pragma unroll
        for (int e = 0; e < 16; ++e) {
            // rows[e] with compile-time e after full unroll -> stays in VGPRs.
            const float4 v = x4[rows[e] * LANES_PER_NODE + c];
            acc.x = fmaxf(acc.x, v.x);
            acc.y = fmaxf(acc.y, v.y);
            acc.z = fmaxf(acc.z, v.z);
            acc.w = fmaxf(acc.w, v.w);
        }
    } else {
        // Generic CSR fallback (correct for any degree / alignment).
        for (int e = start; e < end; ++e) {
            const int row = indices[e];
            const float4 v = x4[row * LANES_PER_NODE + c];
            acc.x = fmaxf(acc.x, v.x);
            acc.y = fmaxf(acc.y, v.y);
            acc.z = fmaxf(acc.z, v.z);
            acc.w = fmaxf(acc.w, v.w);
        }
    }

    reinterpret_cast<float4*>(out)[node * LANES_PER_NODE + c] = acc;
}

extern "C" void kernel_launch(void* const* d_in, const int* in_sizes, int n_in,
                              void* d_out, int out_size, void* d_ws, size_t ws_size,
                              hipStream_t stream) {
    const float* x       = (const float*)d_in[0];
    const int*   indptr  = (const int*)d_in[1];
    const int*   indices = (const int*)d_in[2];
    float*       out     = (float*)d_out;

    const int n_nodes = in_sizes[1] - 1;   // indptr has N+1 entries

    const int grid = (n_nodes + NODES_PER_BLOCK - 1) / NODES_PER_BLOCK;
    seg_max_kernel<<<grid, 256, 0, stream>>>(x, indptr, indices, out, n_nodes);
}